// Round 3
// baseline (308.870 us; speedup 1.0000x reference)
//
#include <hip/hip_runtime.h>

// Self-attention fwd: B=4, S=2048, D=1024, single head.
// Round 11:
//  (a) Spread ds_reads across phases (12/4/8/0 per K-tile) instead of R10's
//      24/0/8/0. bF[4][2] was already live across the whole tile; only read
//      timing moves: p0 reads aF-half0 + bF-half0, p1 reads bF-half1,
//      p2 reads aF-half1, p3 reads nothing (vmcnt+barrier phase). This gives
//      every phase both LDS work and MFMA work -> intra-phase wave skew
//      overlaps LDS with MFMA (the m201 recipe; R10's lumpy version measured
//      37% per-block, exactly the no-overlap serial model).
//  (b) Fuse QK and VWo (independent) into ONE 384-block dispatch via runtime
//      GArgs x2 + ySplit: VWo blocks backfill CUs as QK drains (2tau->1.5tau).
//      All GEMM geometry is now runtime args; hot-loop LDS/MFMA structure
//      unchanged at compile time.
//  Schedule safety (unchanged from R10): a slot's stage is issued only after
//  the barrier following the MFMA that drains that slot's reads. vmcnt(6) at
//  p3 retires through (T+1,A-h1) => tile T+1 resident, 3 half-tiles in
//  flight. Tail drains vmcnt(0).
//
// ws layout (bf16-element offsets over (u16*)d_ws):
//   xb    @ 0          (8388608)   <- VWoT after QKV (xb dead)  [b][do][s]
//   qkv   @ 8388608    (25165824)  [8192][3072] (q|k|v interleaved by col)
//   E     @ 33554432   (16777216)  exp(logits) bf16
//   wqkvT @ 50331648   (3145728)   [3072][1024]  (wqT|wkT|wvT)
//   woT   @ 53477376   (1048576)
//   bqkv  @ 54525952   (6144 u16 = 3072 fp32)
//   l     @ 54532096   (16384 u16 = 8192 fp32 row sums)   end = 109.1 MB

typedef unsigned short u16;
typedef short bf16x8 __attribute__((ext_vector_type(8)));
typedef float f32x4 __attribute__((ext_vector_type(4)));

#define SEQ 2048
#define DIM 1024

__device__ __forceinline__ u16 f2bf(float f) {
    unsigned u = __builtin_bit_cast(unsigned, f);
    u += 0x7fffu + ((u >> 16) & 1u);
    return (u16)(u >> 16);
}

// async 16B global -> LDS (wave-uniform LDS base + lane*16 by construction)
__device__ __forceinline__ void async16(void* lds, const void* gmem) {
    __builtin_amdgcn_global_load_lds(
        (const __attribute__((address_space(1))) void*)gmem,
        (__attribute__((address_space(3))) void*)lds, 16, 0, 0);
}

// ---------------------------------------------------------------------------
// cast x fp32 -> bf16 (blocks 0..8191); bias concat + zero l (blocks 8192+)
__global__ __launch_bounds__(256) void cast_x_kernel(
    const float* __restrict__ x, u16* __restrict__ xb,
    const float* __restrict__ bq, const float* __restrict__ bk,
    const float* __restrict__ bv, float* __restrict__ bqkv,
    float* __restrict__ l)
{
    const int b = blockIdx.x;
    if (b < 8192) {
        const int idx = b * 256 + threadIdx.x;
        float4 v = ((const float4*)x)[idx];
        ushort4 o;
        o.x = f2bf(v.x); o.y = f2bf(v.y); o.z = f2bf(v.z); o.w = f2bf(v.w);
        ((ushort4*)xb)[idx] = o;
    } else {
        const int i = (b - 8192) * 256 + threadIdx.x;   // 0..11263
        if (i < 3072)
            bqkv[i] = (i < 1024) ? bq[i] : (i < 2048) ? bk[i - 1024] : bv[i - 2048];
        else if (i < 3072 + 8192)
            l[i - 3072] = 0.f;
    }
}

// transpose+cast all four 1024x1024 fp32 weights -> bf16 WT[n][k]; z picks W.
__global__ __launch_bounds__(256) void transpose_cast_all(
    const float* __restrict__ W0, const float* __restrict__ W1,
    const float* __restrict__ W2, const float* __restrict__ W3,
    u16* __restrict__ Tqkv, u16* __restrict__ To)
{
    __shared__ float tile[32][33];
    const int z = blockIdx.z;
    const float* W = (z == 0) ? W0 : (z == 1) ? W1 : (z == 2) ? W2 : W3;
    u16* T = (z < 3) ? (Tqkv + (size_t)z * 1048576) : To;

    const int bx = blockIdx.x * 32, by = blockIdx.y * 32;
    const int tx = threadIdx.x, ty = threadIdx.y;
    #pragma unroll
    for (int r = 0; r < 4; ++r)
        tile[ty + r * 8][tx] = W[(size_t)(by + ty + r * 8) * DIM + bx + tx];
    __syncthreads();
    #pragma unroll
    for (int r = 0; r < 4; ++r) {
        const float v = tile[tx][ty + r * 8];   // = W[by+tx][bx+ty+r*8]
        T[(size_t)(bx + ty + r * 8) * DIM + by + tx] = f2bf(v);
    }
}

// ---------------------------------------------------------------------------
// 256x256 8-wave 8-phase GEMM: A[M,K] @ Bt[N,K]^T, runtime geometry.
#define EPI_BF16BIAS 0  // bf16 store of a+bias[col]
#define EPI_BF16     1  // bf16 store of a
#define EPI_ELOGIT   2  // store exp(a*scale) bf16 + atomic row sums into lsum
#define EPI_PVOUT    3  // fp32 store of a/lsum[row] + bias[col]

struct GArgs {
    const u16* A; const u16* Bt; const float* bias;
    u16* C; float* Cf; float* lsum;
    float scale;
    long sA, sB, sC;           // per-z element strides
    int LDA, LDB, LDC, K, epi;
};

#define FENCE() asm volatile("" ::: "memory")

#define MFMA_QUAD(mh, nh)                                                    \
    do {                                                                     \
        __builtin_amdgcn_s_setprio(1);                                       \
        _Pragma("unroll")                                                    \
        for (int ks = 0; ks < 2; ++ks)                                       \
            _Pragma("unroll")                                                \
            for (int q = 0; q < 4; ++q)                                      \
                _Pragma("unroll")                                            \
                for (int nn = 0; nn < 2; ++nn)                               \
                    acc[(mh) * 4 + q][(nh) * 2 + nn] =                       \
                        __builtin_amdgcn_mfma_f32_16x16x32_bf16(             \
                            aF[q][ks], bF[(nh) * 2 + nn][ks],                \
                            acc[(mh) * 4 + q][(nh) * 2 + nn], 0, 0, 0);      \
        __builtin_amdgcn_s_setprio(0);                                       \
    } while (0)

__global__ __launch_bounds__(512, 2) void gemm8w(GArgs g0, GArgs g1, int ySplit)
{
    // [dbuf][mat(A/B)][half][128x64 bf16], swizzled. 128 KiB -> 1 block/CU.
    __shared__ u16 lds[2][2][2][8192];

    const int by = blockIdx.y;
    GArgs g = g0;
    int ty = by;
    if (by >= ySplit) { g = g1; ty = by - ySplit; }

    const int NT = g.K >> 6;        // 64-wide K tiles (>= 2, even not required)
    const int z = blockIdx.z;

    const int t = threadIdx.x;                 // 0..511
    const int wid = t >> 6, lane = t & 63;
    const int wm = wid >> 2, wn = wid & 3;     // wave tile: 128x64 at (wm,wn)
    const int lrow = lane & 15, quad = lane >> 4;
    const int m0 = ty * 256, n0 = blockIdx.x * 256;

    // ---- staging precompute: thread owns 2 x 16B chunks per half-tile ----
    // LDS dest is linear (global_load_lds constraint); the global SOURCE is
    // pre-swizzled with the same involution the reads use. swz(b) =
    // b ^ (((b>>7)&7)<<4): XOR 16B-chunk bits 4-6 with row bits 0-2 (row
    // stride 128B). Bits 7+ untouched => involution.
    int ldsoff[2], offA[2], offB[2];
    #pragma unroll
    for (int p = 0; p < 2; ++p) {
        const int L  = p * 8192 + wid * 1024 + lane * 16;
        const int sL = L ^ (((L >> 7) & 7) << 4);
        const int r  = sL >> 7;             // 0..127 (row within half)
        const int c  = (sL & 127) >> 1;     // bf16 col (multiple of 8)
        ldsoff[p] = L;
        offA[p]   = r * g.LDA + c;
        offB[p]   = r * g.LDB + c;
    }
    const u16* ABase = g.A  + (size_t)z * g.sA + (size_t)m0 * g.LDA;
    const u16* BBase = g.Bt + (size_t)z * g.sB + (size_t)n0 * g.LDB;

    // stage half-tile: sel 0=A-h0 1=A-h1 2=B-h0 3=B-h1, into buf = tile&1
    auto stage = [&](int tile, int sel) {
        const int mat = sel >> 1, half = sel & 1, buf = tile & 1;
        char* dst = (char*)&lds[buf][mat][half][0];
        const int k0 = tile * 64;
        const u16* base = mat ? BBase + (size_t)half * 128 * g.LDB
                              : ABase + (size_t)half * 128 * g.LDA;
        #pragma unroll
        for (int p = 0; p < 2; ++p)
            async16(dst + ldsoff[p], base + k0 + (mat ? offB[p] : offA[p]));
    };

    f32x4 acc[8][4];
    #pragma unroll
    for (int i = 0; i < 8; ++i)
        #pragma unroll
        for (int j = 0; j < 4; ++j)
            acc[i][j] = (f32x4){0.f, 0.f, 0.f, 0.f};

    bf16x8 aF[4][2], bF[4][2];

    // swizzled ds_read of one 16x16x32 fragment (16B per lane)
    auto ldA1 = [&](int buf, int mi, int ks) -> bf16x8 {
        int b = (mi * 16 + lrow) * 128 + ks * 64 + quad * 16;
        b ^= ((b >> 7) & 7) << 4;
        return *(const bf16x8*)((const char*)&lds[buf][0][wm][0] + b);
    };
    auto ldB1 = [&](int buf, int ni, int ks) -> bf16x8 {
        int b = ((wn & 1) * 64 + ni * 16 + lrow) * 128 + ks * 64 + quad * 16;
        b ^= ((b >> 7) & 7) << 4;
        return *(const bf16x8*)((const char*)&lds[buf][1][wn >> 1][0] + b);
    };

    // ---- prologue: tile0 complete + tile1 {B-h0, B-h1, A-h0} in flight ----
    stage(0, 0); stage(0, 1); stage(0, 2); stage(0, 3);
    stage(1, 2); stage(1, 3); stage(1, 0);
    asm volatile("s_waitcnt vmcnt(6)" ::: "memory");   // tile0 resident
    __builtin_amdgcn_s_barrier();

    #pragma unroll 1
    for (int T = 0; T < NT; ++T) {
        const int buf = T & 1;
        const bool s1 = (T + 1 < NT), s2 = (T + 2 < NT);

        // -- p0: read aF-half0 (8) + bF-half0 (4); stage (T+1, A-h1) -> buf^1
        #pragma unroll
        for (int q = 0; q < 4; ++q) {
            aF[q][0] = ldA1(buf, q, 0);
            aF[q][1] = ldA1(buf, q, 1);
        }
        #pragma unroll
        for (int ni = 0; ni < 2; ++ni) {
            bF[ni][0] = ldB1(buf, ni, 0);
            bF[ni][1] = ldB1(buf, ni, 1);
        }
        if (s1) stage(T + 1, 1);
        FENCE(); __builtin_amdgcn_s_barrier();
        MFMA_QUAD(0, 0);                      // drains p0 reads
        FENCE(); __builtin_amdgcn_s_barrier();

        // -- p1: read bF-half1 (4)
        #pragma unroll
        for (int ni = 0; ni < 2; ++ni) {
            bF[2 + ni][0] = ldB1(buf, 2 + ni, 0);
            bF[2 + ni][1] = ldB1(buf, 2 + ni, 1);
        }
        FENCE(); __builtin_amdgcn_s_barrier();
        MFMA_QUAD(0, 1);                      // drains p1 reads -> B slots free
        FENCE(); __builtin_amdgcn_s_barrier();

        // -- p2: read aF-half1 (8); stage (T+2, B-h0/B-h1) -> buf (safe)
        #pragma unroll
        for (int q = 0; q < 4; ++q) {
            aF[q][0] = ldA1(buf, 4 + q, 0);
            aF[q][1] = ldA1(buf, 4 + q, 1);
        }
        if (s2) { stage(T + 2, 2); stage(T + 2, 3); }
        FENCE(); __builtin_amdgcn_s_barrier();
        MFMA_QUAD(1, 1);                      // drains p2 reads -> A slots free
        FENCE(); __builtin_amdgcn_s_barrier();

        // -- p3: no reads; stage (T+2, A-h0); counted vmcnt: retire through
        //    (T+1, A-h1) => tile T+1 resident, 3 half-tiles of T+2 in flight.
        if (s2) {
            stage(T + 2, 0);
            asm volatile("s_waitcnt vmcnt(6)" ::: "memory");
        } else {
            asm volatile("s_waitcnt vmcnt(0)" ::: "memory");
        }
        FENCE(); __builtin_amdgcn_s_barrier();
        MFMA_QUAD(1, 0);                      // bF[0..1] still live from p0
        FENCE(); __builtin_amdgcn_s_barrier();
    }

    // ---- epilogue ----
    const int epi = g.epi;
    u16*   C  = g.C  ? g.C  + (size_t)z * g.sC : nullptr;
    float* Cf = g.Cf ? g.Cf + (size_t)z * g.sC : nullptr;

    #pragma unroll
    for (int mi = 0; mi < 8; ++mi) {
        const int row = m0 + wm * 128 + mi * 16 + quad * 4;  // rows row..row+3
        if (epi == EPI_BF16BIAS) {
            #pragma unroll
            for (int ni = 0; ni < 4; ++ni) {
                const int col = n0 + wn * 64 + ni * 16 + lrow;
                const float bb = g.bias[col];
                const f32x4 a = acc[mi][ni];
                #pragma unroll
                for (int r = 0; r < 4; ++r)
                    C[(size_t)(row + r) * g.LDC + col] = f2bf(a[r] + bb);
            }
        } else if (epi == EPI_BF16) {
            #pragma unroll
            for (int ni = 0; ni < 4; ++ni) {
                const int col = n0 + wn * 64 + ni * 16 + lrow;
                const f32x4 a = acc[mi][ni];
                #pragma unroll
                for (int r = 0; r < 4; ++r)
                    C[(size_t)(row + r) * g.LDC + col] = f2bf(a[r]);
            }
        } else if (epi == EPI_ELOGIT) {
            float rs[4] = {0.f, 0.f, 0.f, 0.f};
            #pragma unroll
            for (int ni = 0; ni < 4; ++ni) {
                const int col = n0 + wn * 64 + ni * 16 + lrow;
                const f32x4 a = acc[mi][ni];
                #pragma unroll
                for (int r = 0; r < 4; ++r) {
                    const float e = __expf(a[r] * g.scale);
                    C[(size_t)(row + r) * g.LDC + col] = f2bf(e);
                    rs[r] += e;
                }
            }
            #pragma unroll
            for (int r = 0; r < 4; ++r) {
                float s = rs[r];
                s += __shfl_xor(s, 1, 64);
                s += __shfl_xor(s, 2, 64);
                s += __shfl_xor(s, 4, 64);
                s += __shfl_xor(s, 8, 64);
                if (lrow == 0)
                    atomicAdd(&g.lsum[(size_t)z * 2048 + row + r], s);
            }
        } else { // EPI_PVOUT
            float linv[4];
            #pragma unroll
            for (int r = 0; r < 4; ++r)
                linv[r] = 1.0f / g.lsum[(size_t)z * 2048 + row + r];
            #pragma unroll
            for (int ni = 0; ni < 4; ++ni) {
                const int col = n0 + wn * 64 + ni * 16 + lrow;
                const float bb = g.bias[col];
                const f32x4 a = acc[mi][ni];
                #pragma unroll
                for (int r = 0; r < 4; ++r)
                    Cf[(size_t)(row + r) * g.LDC + col] = a[r] * linv[r] + bb;
            }
        }
    }
}

// ---------------------------------------------------------------------------
extern "C" void kernel_launch(void* const* d_in, const int* in_sizes, int n_in,
                              void* d_out, int out_size, void* d_ws, size_t ws_size,
                              hipStream_t stream)
{
    const float* x  = (const float*)d_in[0];
    const float* wq = (const float*)d_in[1];
    const float* bq = (const float*)d_in[2];
    const float* wk = (const float*)d_in[3];
    const float* bk = (const float*)d_in[4];
    const float* wv = (const float*)d_in[5];
    const float* bv = (const float*)d_in[6];
    const float* wo = (const float*)d_in[7];
    const float* bo = (const float*)d_in[8];
    float* out = (float*)d_out;

    u16* w16   = (u16*)d_ws;
    u16* xb    = w16;
    u16* qkv   = w16 + 8388608;          // [8192][3072]; q|k|v at col 0/1024/2048
    u16* E     = w16 + 33554432;
    u16* wqkvT = w16 + 50331648;         // [3072][1024] = wqT|wkT|wvT
    u16* woT   = w16 + 53477376;
    float* bqkv = (float*)(w16 + 54525952);
    float* l    = (float*)(w16 + 54532096);
    u16* VWoT  = w16;                    // aliases xb (dead after QKV) [b][1024][2048]

    const u16* q_ = qkv;                 // LDA/LDB = 3072 views
    const u16* k_ = qkv + 1024;
    const u16* v_ = qkv + 2048;

    cast_x_kernel<<<8236, dim3(256), 0, stream>>>(x, xb, bq, bk, bv, bqkv, l);
    transpose_cast_all<<<dim3(32, 32, 4), dim3(32, 8), 0, stream>>>(
        wq, wk, wv, wo, wqkvT, woT);

    // arg sets:            A     Bt     bias   C     Cf    lsum  scale    sA       sB       sC      LDA   LDB   LDC   K    epi
    GArgs gQKV{             xb,   wqkvT, bqkv,  qkv,  0,    0,    1.f,     0,       0,       0,      1024, 1024, 3072, 1024, EPI_BF16BIAS };
    GArgs gQK {             q_,   k_,    0,     E,    0,    l,    0.03125f,6291456, 6291456, 4194304,3072, 3072, 2048, 1024, EPI_ELOGIT   };
    GArgs gVW {             woT,  v_,    0,     VWoT, 0,    0,    1.f,     0,       6291456, 2097152,1024, 3072, 2048, 1024, EPI_BF16     };
    GArgs gPV {             E,    VWoT,  bo,    0,    out,  l,    1.f,     4194304, 2097152, 2097152,2048, 2048, 1024, 2048, EPI_PVOUT    };

    // fused QKV: qkv[8192,3072] = xb @ wqkvT^T + bqkv   (384 blocks)
    gemm8w<<<dim3(12, 32, 1), dim3(512), 0, stream>>>(gQKV, gQKV, 1 << 20);

    // fused dispatch: y<8 -> E[z] = exp((q@k^T)/32) + row sums (256 blocks)
    //                 y>=8 -> VWoT[z] = woT @ v[z]^T           (128 blocks)
    gemm8w<<<dim3(8, 12, 4), dim3(512), 0, stream>>>(gQK, gVW, 8);

    // out[z] = (E[z] @ VWoT[z]^T) / l + bo   fp32 [2048][1024] per batch
    gemm8w<<<dim3(4, 8, 4), dim3(512), 0, stream>>>(gPV, gPV, 1 << 20);
}

// Round 5
// 273.942 us; speedup vs baseline: 1.1275x; 1.1275x over previous
//
#include <hip/hip_runtime.h>

// Self-attention fwd: B=4, S=2048, D=1024, single head.
// Round 13 = Round 12 with the epilogue compile fix (C/Cf were shadowed by
// self-referential locals; now Cz/Cfz). Design rationale unchanged:
//
// R10/R11 measured the 256^2 1-block/CU 8-phase structure at the exact
// reads+MFMA SERIAL sum (~4970 cyc/K-tile): barriers lockstep all 8 waves,
// so LDS-read phases idle the MFMA pipe and vice versa. Fix is structural:
// 2 blocks/CU so the other block fills the idle pipe (m114 mechanism:
// co-resident waves overlap pipes at max, not sum).
//   - tile 128x128, 4 waves (256 thr), wave 64x64 out, acc 4x4 (64 VGPR)
//   - BK=64 double-buffered LDS = 64 KiB -> exactly 2 blocks/CU; 128B rows
//     keep the proven-free 3-bit XOR swizzle (byte ^= ((byte>>7)&7)<<4)
//   - loop: vmcnt(counted) -> barrier -> reads+MFMA -> barrier -> stage(T+2)
//     (stage overwrites a buffer whose reads drained at the barrier; vmcnt
//     stays counted (8) mid-loop, 2 tiles in flight, drains only at tail)
//   - exact grid packing at 512-block capacity: QKV 1536=3 passes, QK 1024=2,
//     VWo 512=1, PV 512=1. Zero tail idle.
// Epilogues + associativity rewrite out = P @ (V*Wo) kept.
//
// ws layout (bf16-element offsets over (u16*)d_ws):
//   xb    @ 0          (8388608)   <- VWoT after QKV (xb dead)  [b][do][s]
//   qkv   @ 8388608    (25165824)  [8192][3072] (q|k|v interleaved by col)
//   E     @ 33554432   (16777216)  exp(logits) bf16
//   wqkvT @ 50331648   (3145728)   [3072][1024]  (wqT|wkT|wvT)
//   woT   @ 53477376   (1048576)
//   bqkv  @ 54525952   (6144 u16 = 3072 fp32)
//   l     @ 54532096   (16384 u16 = 8192 fp32 row sums)   end = 109.1 MB

typedef unsigned short u16;
typedef short bf16x8 __attribute__((ext_vector_type(8)));
typedef float f32x4 __attribute__((ext_vector_type(4)));

#define SEQ 2048
#define DIM 1024

__device__ __forceinline__ u16 f2bf(float f) {
    unsigned u = __builtin_bit_cast(unsigned, f);
    u += 0x7fffu + ((u >> 16) & 1u);
    return (u16)(u >> 16);
}

// async 16B global -> LDS (wave-uniform LDS base + lane*16 by construction)
__device__ __forceinline__ void async16(void* lds, const void* gmem) {
    __builtin_amdgcn_global_load_lds(
        (const __attribute__((address_space(1))) void*)gmem,
        (__attribute__((address_space(3))) void*)lds, 16, 0, 0);
}

#define FENCE() asm volatile("" ::: "memory")

// ---------------------------------------------------------------------------
// cast x fp32 -> bf16 (blocks 0..8191); bias concat + zero l (blocks 8192+)
__global__ __launch_bounds__(256) void cast_x_kernel(
    const float* __restrict__ x, u16* __restrict__ xb,
    const float* __restrict__ bq, const float* __restrict__ bk,
    const float* __restrict__ bv, float* __restrict__ bqkv,
    float* __restrict__ l)
{
    const int b = blockIdx.x;
    if (b < 8192) {
        const int idx = b * 256 + threadIdx.x;
        float4 v = ((const float4*)x)[idx];
        ushort4 o;
        o.x = f2bf(v.x); o.y = f2bf(v.y); o.z = f2bf(v.z); o.w = f2bf(v.w);
        ((ushort4*)xb)[idx] = o;
    } else {
        const int i = (b - 8192) * 256 + threadIdx.x;   // 0..11263
        if (i < 3072)
            bqkv[i] = (i < 1024) ? bq[i] : (i < 2048) ? bk[i - 1024] : bv[i - 2048];
        else if (i < 3072 + 8192)
            l[i - 3072] = 0.f;
    }
}

// transpose+cast all four 1024x1024 fp32 weights -> bf16 WT[n][k]; z picks W.
__global__ __launch_bounds__(256) void transpose_cast_all(
    const float* __restrict__ W0, const float* __restrict__ W1,
    const float* __restrict__ W2, const float* __restrict__ W3,
    u16* __restrict__ Tqkv, u16* __restrict__ To)
{
    __shared__ float tile[32][33];
    const int z = blockIdx.z;
    const float* W = (z == 0) ? W0 : (z == 1) ? W1 : (z == 2) ? W2 : W3;
    u16* T = (z < 3) ? (Tqkv + (size_t)z * 1048576) : To;

    const int bx = blockIdx.x * 32, by = blockIdx.y * 32;
    const int tx = threadIdx.x, ty = threadIdx.y;
    #pragma unroll
    for (int r = 0; r < 4; ++r)
        tile[ty + r * 8][tx] = W[(size_t)(by + ty + r * 8) * DIM + bx + tx];
    __syncthreads();
    #pragma unroll
    for (int r = 0; r < 4; ++r) {
        const float v = tile[tx][ty + r * 8];   // = W[by+tx][bx+ty+r*8]
        T[(size_t)(bx + ty + r * 8) * DIM + by + tx] = f2bf(v);
    }
}

// ---------------------------------------------------------------------------
// 128x128-tile 4-wave GEMM: A[M,K] @ Bt[N,K]^T. 2 blocks/CU (64 KiB LDS).
#define EPI_BF16BIAS 0  // bf16 store of a+bias[col]
#define EPI_BF16     1  // bf16 store of a
#define EPI_ELOGIT   2  // store exp(a*scale) bf16 + atomic row sums into lsum
#define EPI_PVOUT    3  // fp32 store of a/lsum[row] + bias[col]

template<int EPI, int K, int LDA, int LDB, int LDC>
__global__ __launch_bounds__(256, 2) void gemm4w(
    const u16* __restrict__ A, const u16* __restrict__ Bt,
    const float* __restrict__ bias, u16* __restrict__ C,
    float* __restrict__ Cf, float* __restrict__ lsum,
    float scale, long sA, long sB, long sC)
{
    // [dbuf][mat(A/B)][128x64 bf16], 16 KB each = 64 KiB total.
    __shared__ u16 lds[2][2][8192];

    constexpr int NT = K / 64;      // 64-wide K tiles

    const int z = blockIdx.z;
    const int t = threadIdx.x;                 // 0..255
    const int wid = t >> 6, lane = t & 63;
    const int wm = wid >> 1, wn = wid & 1;     // wave tile: 64x64 at (wm,wn)
    const int lrow = lane & 15, quad = lane >> 4;
    const int m0 = blockIdx.y * 128, n0 = blockIdx.x * 128;

    const u16* ABase = A  + (size_t)z * sA + (size_t)m0 * LDA;
    const u16* BBase = Bt + (size_t)z * sB + (size_t)n0 * LDB;

    // ---- staging: 1024 16B chunks per 128x64 tile; thread owns 4 per mat.
    // LDS dest linear (global_load_lds constraint); global SOURCE column is
    // pre-swizzled with the read involution: chunk' = chunk ^ (row & 7)
    // (byte bits 4-6 ^= row bits 0-2; row stride 128 B).
    int srow[4], scolOff[4];
    #pragma unroll
    for (int p = 0; p < 4; ++p) {
        const int slot = p * 256 + t;          // 0..1023
        const int row  = slot >> 3;            // 0..127
        const int c8   = (slot & 7) ^ (row & 7);
        srow[p] = row; scolOff[p] = c8 * 8;
    }

    auto stage = [&](int tile, int buf) {
        const int k0 = tile * 64;
        #pragma unroll
        for (int p = 0; p < 4; ++p) {
            const int slot = p * 256 + t;
            async16(&lds[buf][0][slot * 8],
                    ABase + (size_t)srow[p] * LDA + k0 + scolOff[p]);
        }
        #pragma unroll
        for (int p = 0; p < 4; ++p) {
            const int slot = p * 256 + t;
            async16(&lds[buf][1][slot * 8],
                    BBase + (size_t)srow[p] * LDB + k0 + scolOff[p]);
        }
    };

    f32x4 acc[4][4];
    #pragma unroll
    for (int i = 0; i < 4; ++i)
        #pragma unroll
        for (int j = 0; j < 4; ++j)
            acc[i][j] = (f32x4){0.f, 0.f, 0.f, 0.f};

    // swizzled ds_read of one 16x16x32 fragment (16B per lane)
    auto ldA1 = [&](int buf, int mi, int ks) -> bf16x8 {
        int b = (wm * 64 + mi * 16 + lrow) * 128 + ks * 64 + quad * 16;
        b ^= ((b >> 7) & 7) << 4;
        return *(const bf16x8*)((const char*)&lds[buf][0][0] + b);
    };
    auto ldB1 = [&](int buf, int ni, int ks) -> bf16x8 {
        int b = (wn * 64 + ni * 16 + lrow) * 128 + ks * 64 + quad * 16;
        b ^= ((b >> 7) & 7) << 4;
        return *(const bf16x8*)((const char*)&lds[buf][1][0] + b);
    };

    // ---- prologue: tiles 0,1 in flight (8 wave-loads each) ----
    stage(0, 0);
    stage(1, 1);

    #pragma unroll 1
    for (int T = 0; T < NT; ++T) {
        const int buf = T & 1;
        // retire tile T's 8 loads; keep T+1's 8 in flight (counted, not 0)
        if (T + 1 < NT) asm volatile("s_waitcnt vmcnt(8)" ::: "memory");
        else            asm volatile("s_waitcnt vmcnt(0)" ::: "memory");
        __builtin_amdgcn_s_barrier();

        #pragma unroll
        for (int ks = 0; ks < 2; ++ks) {
            bf16x8 aF[4], bF[4];
            #pragma unroll
            for (int mi = 0; mi < 4; ++mi) aF[mi] = ldA1(buf, mi, ks);
            #pragma unroll
            for (int ni = 0; ni < 4; ++ni) bF[ni] = ldB1(buf, ni, ks);
            __builtin_amdgcn_s_setprio(1);
            #pragma unroll
            for (int mi = 0; mi < 4; ++mi)
                #pragma unroll
                for (int ni = 0; ni < 4; ++ni)
                    acc[mi][ni] = __builtin_amdgcn_mfma_f32_16x16x32_bf16(
                        aF[mi], bF[ni], acc[mi][ni], 0, 0, 0);
            __builtin_amdgcn_s_setprio(0);
        }
        FENCE();
        __builtin_amdgcn_s_barrier();   // buf's reads drained -> safe to restage
        if (T + 2 < NT) stage(T + 2, buf);
    }

    // ---- epilogue ----
    u16*   Cz  = C  + (size_t)z * sC;
    float* Cfz = Cf ? Cf + (size_t)z * sC : nullptr;

    #pragma unroll
    for (int mi = 0; mi < 4; ++mi) {
        const int row = m0 + wm * 64 + mi * 16 + quad * 4;   // rows row..row+3
        if (EPI == EPI_BF16BIAS) {
            #pragma unroll
            for (int ni = 0; ni < 4; ++ni) {
                const int col = n0 + wn * 64 + ni * 16 + lrow;
                const float bb = bias[col];
                const f32x4 a = acc[mi][ni];
                #pragma unroll
                for (int r = 0; r < 4; ++r)
                    Cz[(size_t)(row + r) * LDC + col] = f2bf(a[r] + bb);
            }
        } else if (EPI == EPI_BF16) {
            #pragma unroll
            for (int ni = 0; ni < 4; ++ni) {
                const int col = n0 + wn * 64 + ni * 16 + lrow;
                const f32x4 a = acc[mi][ni];
                #pragma unroll
                for (int r = 0; r < 4; ++r)
                    Cz[(size_t)(row + r) * LDC + col] = f2bf(a[r]);
            }
        } else if (EPI == EPI_ELOGIT) {
            float rs[4] = {0.f, 0.f, 0.f, 0.f};
            #pragma unroll
            for (int ni = 0; ni < 4; ++ni) {
                const int col = n0 + wn * 64 + ni * 16 + lrow;
                const f32x4 a = acc[mi][ni];
                #pragma unroll
                for (int r = 0; r < 4; ++r) {
                    const float e = __expf(a[r] * scale);
                    Cz[(size_t)(row + r) * LDC + col] = f2bf(e);
                    rs[r] += e;
                }
            }
            #pragma unroll
            for (int r = 0; r < 4; ++r) {
                float s = rs[r];
                s += __shfl_xor(s, 1, 64);
                s += __shfl_xor(s, 2, 64);
                s += __shfl_xor(s, 4, 64);
                s += __shfl_xor(s, 8, 64);
                if (lrow == 0)
                    atomicAdd(&lsum[(size_t)z * 2048 + row + r], s);
            }
        } else { // EPI_PVOUT
            float linv[4];
            #pragma unroll
            for (int r = 0; r < 4; ++r)
                linv[r] = 1.0f / lsum[(size_t)z * 2048 + row + r];
            #pragma unroll
            for (int ni = 0; ni < 4; ++ni) {
                const int col = n0 + wn * 64 + ni * 16 + lrow;
                const float bb = bias[col];
                const f32x4 a = acc[mi][ni];
                #pragma unroll
                for (int r = 0; r < 4; ++r)
                    Cfz[(size_t)(row + r) * LDC + col] = a[r] * linv[r] + bb;
            }
        }
    }
}

// ---------------------------------------------------------------------------
extern "C" void kernel_launch(void* const* d_in, const int* in_sizes, int n_in,
                              void* d_out, int out_size, void* d_ws, size_t ws_size,
                              hipStream_t stream)
{
    const float* x  = (const float*)d_in[0];
    const float* wq = (const float*)d_in[1];
    const float* bq = (const float*)d_in[2];
    const float* wk = (const float*)d_in[3];
    const float* bk = (const float*)d_in[4];
    const float* wv = (const float*)d_in[5];
    const float* bv = (const float*)d_in[6];
    const float* wo = (const float*)d_in[7];
    const float* bo = (const float*)d_in[8];
    float* out = (float*)d_out;

    u16* w16   = (u16*)d_ws;
    u16* xb    = w16;
    u16* qkv   = w16 + 8388608;          // [8192][3072]; q|k|v at col 0/1024/2048
    u16* E     = w16 + 33554432;
    u16* wqkvT = w16 + 50331648;         // [3072][1024] = wqT|wkT|wvT
    u16* woT   = w16 + 53477376;
    float* bqkv = (float*)(w16 + 54525952);
    float* l    = (float*)(w16 + 54532096);
    u16* VWoT  = w16;                    // aliases xb (dead after QKV) [b][1024][2048]

    const u16* q_ = qkv;                 // LDA/LDB = 3072 views
    const u16* k_ = qkv + 1024;
    const u16* v_ = qkv + 2048;

    cast_x_kernel<<<8236, dim3(256), 0, stream>>>(x, xb, bq, bk, bv, bqkv, l);
    transpose_cast_all<<<dim3(32, 32, 4), dim3(32, 8), 0, stream>>>(
        wq, wk, wv, wo, wqkvT, woT);

    // fused QKV: qkv[8192,3072] = xb @ wqkvT^T + bqkv   (24x64 = 1536 blocks)
    gemm4w<EPI_BF16BIAS, 1024, 1024, 1024, 3072>
        <<<dim3(24, 64, 1), dim3(256), 0, stream>>>(
            xb, wqkvT, bqkv, qkv, nullptr, nullptr, 1.f, 0, 0, 0);

    // E[z] = exp((q[z] @ k[z]^T)/32) bf16, + row sums into l  (1024 blocks)
    gemm4w<EPI_ELOGIT, 1024, 3072, 3072, 2048>
        <<<dim3(16, 16, 4), dim3(256), 0, stream>>>(
            q_, k_, nullptr, E, nullptr, l, 0.03125f,
            6291456, 6291456, 4194304);

    // VWoT[z] = woT @ v[z]^T   [1024][2048] bf16 per batch  (512 blocks)
    gemm4w<EPI_BF16, 1024, 1024, 3072, 2048>
        <<<dim3(16, 8, 4), dim3(256), 0, stream>>>(
            woT, v_, nullptr, VWoT, nullptr, nullptr, 1.f,
            0, 6291456, 2097152);

    // out[z] = (E[z] @ VWoT[z]^T) / l + bo   fp32 [2048][1024]  (512 blocks)
    gemm4w<EPI_PVOUT, 2048, 2048, 2048, 1024>
        <<<dim3(8, 16, 4), dim3(256), 0, stream>>>(
            E, VWoT, bo, nullptr, out, l, 1.f,
            4194304, 2097152, 2097152);
}